// Round 2
// baseline (206.593 us; speedup 1.0000x reference)
//
#include <hip/hip_runtime.h>

// YOLOv1 loss, S=14, B=2, C=20, 30 fp32 channels/cell, 802816 cells.
// Round-3: flat 72us across 8 and 11.5 waves/CU proved wave count is not
// the limiter; the per-wave vmcnt(0) full drains left loads in flight only
// ~half the time. New structure: persistent 1-wave blocks (1280 = 5/CU),
// each wave pipelines 64-cell tiles with a double-buffered LDS tile
// (pred+target staged together) and COUNTED vmcnt: issue next tile's 18
// global_load_lds, then s_waitcnt vmcnt(18) so the previous tile is ready
// while the next 18 stay in flight under ds_read+compute. vmcnt never
// drains to 0 in the steady state. One atomic per wave.

#define NT   12544   // 64-cell wave tiles (802816 / 64)
#define NBLK 1280    // 5 blocks/CU x 256 CU

__global__ void zero_out_kernel(float* out) { out[0] = 0.0f; }

__device__ __forceinline__ void gll16(const void* g, void* l) {
    __builtin_amdgcn_global_load_lds(
        (const __attribute__((address_space(1))) void*)(uintptr_t)g,
        (__attribute__((address_space(3))) void*)(uintptr_t)l, 16, 0, 0);
}
__device__ __forceinline__ void gll4(const void* g, void* l) {
    __builtin_amdgcn_global_load_lds(
        (const __attribute__((address_space(1))) void*)(uintptr_t)g,
        (__attribute__((address_space(3))) void*)(uintptr_t)l, 4, 0, 0);
}

// Stage one 64-cell tile of BOTH arrays (2 x 7680 B, linear) -> LDS buffer.
// Per array: 7 x width16 covers [0,7168); 2 x width4 cover the 512 B tail.
// Exactly 18 global_load_lds issued (the vmcnt(18) count below).
__device__ __forceinline__ void stage_tile(const float* __restrict__ gp,
                                           const float* __restrict__ gt,
                                           float* lds, int lane)
{
    const char* pb = (const char*)gp;
    const char* tb = (const char*)gt;
    char* lp = (char*)lds;
    char* lt = lp + 7680;
    #pragma unroll
    for (int i = 0; i < 7; ++i)
        gll16(pb + i * 1024 + lane * 16, lp + i * 1024);
    gll4(pb + 7168 + lane * 4, lp + 7168);
    gll4(pb + 7424 + lane * 4, lp + 7424);
    #pragma unroll
    for (int i = 0; i < 7; ++i)
        gll16(tb + i * 1024 + lane * 16, lt + i * 1024);
    gll4(tb + 7168 + lane * 4, lt + 7168);
    gll4(tb + 7424 + lane * 4, lt + 7424);
}

__global__ __launch_bounds__(64) void yolo_loss_kernel(
    const float* __restrict__ pred, const float* __restrict__ target,
    float* __restrict__ out)
{
    // 2 pipeline buffers x (1920 pred + 1920 target floats) = 30720 B
    // -> exactly 5 blocks/CU on the 160 KiB LDS pool.
    __shared__ __align__(16) float sbuf[2][3840];

    const int lane = threadIdx.x;           // 64-thread block = one wave
    const float invS = 1.0f / 14.0f;

    float acc = 0.0f;
    int t = blockIdx.x;                     // wave-uniform tile index
    stage_tile(pred + (size_t)t * 1920, target + (size_t)t * 1920,
               sbuf[0], lane);
    int cur = 0;

    while (t < NT) {
        const int tn = t + NBLK;
        if (tn < NT) {
            stage_tile(pred + (size_t)tn * 1920, target + (size_t)tn * 1920,
                       sbuf[cur ^ 1], lane);
            // wait only for the PREVIOUS tile's 18 loads; keep 18 in flight
            asm volatile("s_waitcnt vmcnt(18)" ::: "memory");
        } else {
            asm volatile("s_waitcnt vmcnt(0)" ::: "memory");
        }

        // ---- LDS -> own cell (15x ds_read_b64 each; 2-way banks = free)
        float pv[30], tv[30];
        const float2* rp = (const float2*)&sbuf[cur][lane * 30];
        const float2* rt = (const float2*)&sbuf[cur][1920 + lane * 30];
        #pragma unroll
        for (int j = 0; j < 15; ++j) {
            float2 a = rp[j]; pv[2*j] = a.x; pv[2*j+1] = a.y;
            float2 b = rt[j]; tv[2*j] = b.x; tv[2*j+1] = b.y;
        }
        // retire all ds_reads before the next iteration's DMA may overwrite
        asm volatile("s_waitcnt lgkmcnt(0)" ::: "memory");

        // ---- per-cell loss (identical math to the verified kernel)
        const bool obj = tv[4] > 0.0f;

        float tcx = tv[0] * invS, tcy = tv[1] * invS;
        float thw = 0.5f * tv[2], thh = 0.5f * tv[3];
        float tx1 = tcx - thw, ty1 = tcy - thh;
        float tx2 = tcx + thw, ty2 = tcy + thh;
        float area_t = (tx2 - tx1) * (ty2 - ty1);

        float iou0 = 0.0f, iou1 = 0.0f;
        #pragma unroll
        for (int b = 0; b < 2; ++b) {
            float cx = pv[5*b + 0] * invS, cy = pv[5*b + 1] * invS;
            float hw = 0.5f * pv[5*b + 2], hh = 0.5f * pv[5*b + 3];
            float x1 = cx - hw, y1 = cy - hh, x2 = cx + hw, y2 = cy + hh;
            float lx = fmaxf(x1, tx1), ly = fmaxf(y1, ty1);
            float rx = fminf(x2, tx2), ry = fminf(y2, ty2);
            float w = fmaxf(rx - lx, 0.0f), h = fmaxf(ry - ly, 0.0f);
            float inter = w * h;
            float area_p = (x2 - x1) * (y2 - y1);
            float iou = inter / (area_p + area_t - inter);
            if (b == 0) iou0 = iou; else iou1 = iou;
        }
        const bool  sel     = iou1 > iou0;   // jnp.argmax: first max wins
        const float max_iou = fmaxf(iou0, iou1);

        float local;
        if (obj) {
            float pbx = sel ? pv[5] : pv[0];
            float pby = sel ? pv[6] : pv[1];
            float pbw = sel ? pv[7] : pv[2];
            float pbh = sel ? pv[8] : pv[3];
            float pbc = sel ? pv[9] : pv[4];

            float dx = pbx - tv[0], dy = pby - tv[1];
            float loss_xy = dx*dx + dy*dy;

            float sw_ = sqrtf(pbw) - sqrtf(tv[2]);
            float sh_ = sqrtf(pbh) - sqrtf(tv[3]);
            float loss_wh = sw_*sw_ + sh_*sh_;

            float dob = pbc - max_iou;
            float loss_obj = dob * dob;

            float loss_cls = 0.0f;
            #pragma unroll
            for (int c = 0; c < 20; ++c) {
                float d = pv[10 + c] - tv[10 + c];
                loss_cls = fmaf(d, d, loss_cls);
            }
            local = 5.0f * (loss_xy + loss_wh) + loss_obj + loss_cls;
        } else {
            float d0 = pv[4] - tv[4];
            float d1 = pv[9] - tv[9];
            local = 0.5f * (d0*d0 + d1*d1);
        }
        acc += local;

        cur ^= 1;
        t = tn;
    }

    // ---- wave-64 shuffle reduction -> one atomic per wave
    #pragma unroll
    for (int off = 32; off > 0; off >>= 1)
        acc += __shfl_down(acc, off, 64);
    if (lane == 0)
        atomicAdd(out, acc * (1.0f / 4096.0f));
}

extern "C" void kernel_launch(void* const* d_in, const int* in_sizes, int n_in,
                              void* d_out, int out_size, void* d_ws, size_t ws_size,
                              hipStream_t stream) {
    const float* pred   = (const float*)d_in[0];
    const float* target = (const float*)d_in[1];
    float* out = (float*)d_out;

    zero_out_kernel<<<1, 1, 0, stream>>>(out);
    yolo_loss_kernel<<<NBLK, 64, 0, stream>>>(pred, target, out);
}